// Round 3
// baseline (3888.505 us; speedup 1.0000x reference)
//
#include <hip/hip_runtime.h>
#include <hip/hip_bf16.h>

#define CDIM 2048
#define HDIM 8192
#define BDIM 8
#define TDIM 2048
#define BT (BDIM*TDIM)

typedef __attribute__((ext_vector_type(8))) __bf16 bf16x8;
typedef __attribute__((ext_vector_type(4))) float f32x4;

#define GLOAD_LDS16(g, l) __builtin_amdgcn_global_load_lds( \
    (__attribute__((address_space(1))) const void*)(g),      \
    (__attribute__((address_space(3))) void*)(l), 16, 0, 0)

__device__ __forceinline__ unsigned short f2bf(float f) {
  unsigned int u = __float_as_uint(f);
  u += 0x7FFF + ((u >> 16) & 1);
  return (unsigned short)(u >> 16);
}

__device__ __forceinline__ float bf2f(unsigned short h) {
  unsigned int u = ((unsigned int)h) << 16;
  return __uint_as_float(u);
}

__device__ __forceinline__ float sigmoidf_(float x) {
  return 1.f / (1.f + expf(-x));
}

// ---------------- sentinel: marks "workspace too small" unambiguously -----
__global__ void sentinel_kernel(float* out) {
  if (threadIdx.x == 0) out[0] = 12345.0f;
}

// ---------------- fp32 -> bf16 weight conversion ----------------
__global__ __launch_bounds__(256) void f2bf_kernel(const float* __restrict__ in,
                                                   unsigned short* __restrict__ out,
                                                   int n4) {
  int i = blockIdx.x * 256 + threadIdx.x;
  int stride = gridDim.x * 256;
  for (; i < n4; i += stride) {
    float4 v = ((const float4*)in)[i];
    unsigned int lo = (unsigned int)f2bf(v.x) | ((unsigned int)f2bf(v.y) << 16);
    unsigned int hi = (unsigned int)f2bf(v.z) | ((unsigned int)f2bf(v.w) << 16);
    ((uint2*)out)[i] = make_uint2(lo, hi);
  }
}

// ---------------- fused LayerNorm + time_shift + mix -> bf16 ----------------
template<int NOUT>
__global__ __launch_bounds__(256) void ln_mix(
    const float* __restrict__ x, const float* __restrict__ lnw, const float* __restrict__ lnb,
    const float* __restrict__ f0v, const float* __restrict__ f1v, const float* __restrict__ f2v,
    unsigned short* __restrict__ o0, unsigned short* __restrict__ o1, unsigned short* __restrict__ o2)
{
  __shared__ float red[4][4];
  const int bt = blockIdx.x;
  const int t = bt & (TDIM - 1);
  const float* row = x + (size_t)bt * CDIM;
  const int base = threadIdx.x * 8;
  float a[8], b[8];
  *(float4*)&a[0] = *(const float4*)&row[base];
  *(float4*)&a[4] = *(const float4*)&row[base + 4];
  const bool hasprev = (t > 0);
  if (hasprev) {
    *(float4*)&b[0] = *(const float4*)&row[base - CDIM];
    *(float4*)&b[4] = *(const float4*)&row[base + 4 - CDIM];
  } else {
#pragma unroll
    for (int j = 0; j < 8; ++j) b[j] = 0.f;
  }
  float s0 = 0.f, q0 = 0.f, s1 = 0.f, q1 = 0.f;
#pragma unroll
  for (int j = 0; j < 8; ++j) {
    s0 += a[j]; q0 += a[j] * a[j];
    s1 += b[j]; q1 += b[j] * b[j];
  }
#pragma unroll
  for (int o = 32; o > 0; o >>= 1) {
    s0 += __shfl_down(s0, o); q0 += __shfl_down(q0, o);
    s1 += __shfl_down(s1, o); q1 += __shfl_down(q1, o);
  }
  const int wv = threadIdx.x >> 6;
  if ((threadIdx.x & 63) == 0) { red[wv][0] = s0; red[wv][1] = q0; red[wv][2] = s1; red[wv][3] = q1; }
  __syncthreads();
  s0 = red[0][0] + red[1][0] + red[2][0] + red[3][0];
  q0 = red[0][1] + red[1][1] + red[2][1] + red[3][1];
  s1 = red[0][2] + red[1][2] + red[2][2] + red[3][2];
  q1 = red[0][3] + red[1][3] + red[2][3] + red[3][3];
  const float inv = 1.f / (float)CDIM;
  float mu0 = s0 * inv, r0 = rsqrtf(q0 * inv - mu0 * mu0 + 1e-5f);
  float mu1 = s1 * inv, r1 = rsqrtf(q1 * inv - mu1 * mu1 + 1e-5f);
  union { unsigned short u[8]; uint4 v; } w0, w1, w2;
#pragma unroll
  for (int j = 0; j < 8; ++j) {
    int c = base + j;
    float lw = lnw[c], lb = lnb[c];
    float xn = (a[j] - mu0) * r0 * lw + lb;
    float xx = hasprev ? ((b[j] - mu1) * r1 * lw + lb) : 0.f;
    float f0 = f0v[c]; w0.u[j] = f2bf(xn * f0 + xx * (1.f - f0));
    float f1 = f1v[c]; w1.u[j] = f2bf(xn * f1 + xx * (1.f - f1));
    if (NOUT == 3) { float f2 = f2v[c]; w2.u[j] = f2bf(xn * f2 + xx * (1.f - f2)); }
  }
  size_t ob = (size_t)bt * CDIM + base;
  *(uint4*)&o0[ob] = w0.v;
  *(uint4*)&o1[ob] = w1.v;
  if (NOUT == 3) *(uint4*)&o2[ob] = w2.v;
}

// ---------------- WKV recurrence: one thread per (b,c) channel ----------------
// k: fp32 (lives in d_out); v: bf16, att written IN-PLACE over v.
__global__ __launch_bounds__(64) void wkv_kernel(
    const float* __restrict__ td, const float* __restrict__ tf,
    const float* __restrict__ k,
    unsigned short* __restrict__ vatt)
{
  const int idx = blockIdx.x * 64 + threadIdx.x;
  const int c = idx & (CDIM - 1);
  const int b = idx >> 11;
  const float w = -expf(td[c]);
  const float u = tf[c];
  const float* kp = k + (size_t)b * TDIM * CDIM + c;
  unsigned short* vp = vatt + (size_t)b * TDIM * CDIM + c;
  float aa = 0.f, bb = 0.f, pp = -1e38f;
  for (int t = 0; t < TDIM; ++t) {
    size_t o = (size_t)t * CDIM;
    float kt = kp[o];
    float vt = bf2f(vp[o]);
    float ww = u + kt;
    float p = fmaxf(pp, ww);
    float e1 = expf(pp - p);
    float e2 = expf(ww - p);
    float y = (e1 * aa + e2 * vt) / (e1 * bb + e2);
    vp[o] = f2bf(y);                // att over v (read-before-write, own column)
    float ww2 = pp + w;
    float p2 = fmaxf(ww2, kt);
    float e1b = expf(ww2 - p2);
    float e2b = expf(kt - p2);
    aa = e1b * aa + e2b * vt;
    bb = e1b * bb + e2b;
    pp = p2;
  }
}

// ---------------- bf16 MFMA GEMM, B-transposed: out[m,n] = sum_k A[m,k]*W[n,k] ----
// m97 structure: 128x128 tile, BK=32, 4 waves (2x2), global_load_lds width 16.
#define EPI_F32 0        // f32 store
#define EPI_BF 1         // bf16 store
#define EPI_ADDX 2       // f32: xin + acc
#define EPI_SIGMUL_BF 3  // bf16: sigmoid(acc) * bf16(other)
#define EPI_RELU2_BF 4   // bf16: relu(acc)^2
#define EPI_SIG_BF 5     // bf16: sigmoid(acc)
#define EPI_MULBF_ADDX 6 // f32 in-place: xin + bf16(other) * acc

template<int EPI>
__global__ __launch_bounds__(256) void gemm_bt(
    const unsigned short* __restrict__ A,
    const unsigned short* __restrict__ Bw,
    void* __restrict__ outp,
    const float* __restrict__ xin,
    const void* __restrict__ otherp,
    int M, int N, int K)
{
  __shared__ unsigned short As[128 * 32];
  __shared__ unsigned short Bs[128 * 32];
  const int tid = threadIdx.x;
  const int wid = tid >> 6;
  const int lane = tid & 63;
  const int nTN = N >> 7;
  const int tm = blockIdx.x / nTN;
  const int tn = blockIdx.x % nTN;
  const int m0 = tm << 7;
  const int n0 = tn << 7;
  const int wr = wid >> 1, wc = wid & 1;

  f32x4 acc[4][4];
#pragma unroll
  for (int i = 0; i < 4; ++i)
#pragma unroll
    for (int j = 0; j < 4; ++j)
      acc[i][j] = (f32x4){0.f, 0.f, 0.f, 0.f};

  const int srow = lane >> 2;
  const int scol = (lane & 3) * 8;
  const int s0 = wid * 2;

  const unsigned short* gA0 = A + (size_t)(m0 + s0 * 16 + srow) * K + scol;
  const unsigned short* gA1 = A + (size_t)(m0 + (s0 + 1) * 16 + srow) * K + scol;
  const unsigned short* gB0 = Bw + (size_t)(n0 + s0 * 16 + srow) * K + scol;
  const unsigned short* gB1 = Bw + (size_t)(n0 + (s0 + 1) * 16 + srow) * K + scol;
  unsigned short* lA0 = &As[s0 * 512];
  unsigned short* lA1 = &As[(s0 + 1) * 512];
  unsigned short* lB0 = &Bs[s0 * 512];
  unsigned short* lB1 = &Bs[(s0 + 1) * 512];

  const int frow = lane & 15;
  const int fk = (lane >> 4) * 8;

  for (int k0 = 0; k0 < K; k0 += 32) {
    __syncthreads();
    GLOAD_LDS16(gA0 + k0, lA0);
    GLOAD_LDS16(gA1 + k0, lA1);
    GLOAD_LDS16(gB0 + k0, lB0);
    GLOAD_LDS16(gB1 + k0, lB1);
    asm volatile("s_waitcnt vmcnt(0)" ::: "memory");
    __syncthreads();
    bf16x8 af[4], bfr[4];
#pragma unroll
    for (int mi = 0; mi < 4; ++mi)
      af[mi] = *(const bf16x8*)&As[(wr * 64 + mi * 16 + frow) * 32 + fk];
#pragma unroll
    for (int ni = 0; ni < 4; ++ni)
      bfr[ni] = *(const bf16x8*)&Bs[(wc * 64 + ni * 16 + frow) * 32 + fk];
#pragma unroll
    for (int mi = 0; mi < 4; ++mi)
#pragma unroll
      for (int ni = 0; ni < 4; ++ni)
        acc[mi][ni] = __builtin_amdgcn_mfma_f32_16x16x32_bf16(af[mi], bfr[ni], acc[mi][ni], 0, 0, 0);
  }

  // epilogue: C/D layout col=lane&15, row=(lane>>4)*4+r
  const int colb = n0 + wc * 64 + (lane & 15);
  const int rowb = m0 + wr * 64 + (lane >> 4) * 4;
#pragma unroll
  for (int mi = 0; mi < 4; ++mi) {
#pragma unroll
    for (int ni = 0; ni < 4; ++ni) {
#pragma unroll
      for (int r = 0; r < 4; ++r) {
        int row = rowb + mi * 16 + r;
        int col = colb + ni * 16;
        size_t off = (size_t)row * N + col;
        float vv = acc[mi][ni][r];
        if (EPI == EPI_F32) {
          ((float*)outp)[off] = vv;
        } else if (EPI == EPI_BF) {
          ((unsigned short*)outp)[off] = f2bf(vv);
        } else if (EPI == EPI_ADDX) {
          ((float*)outp)[off] = xin[off] + vv;
        } else if (EPI == EPI_SIGMUL_BF) {
          float at = bf2f(((const unsigned short*)otherp)[off]);
          ((unsigned short*)outp)[off] = f2bf(sigmoidf_(vv) * at);
        } else if (EPI == EPI_RELU2_BF) {
          float rr = fmaxf(vv, 0.f);
          ((unsigned short*)outp)[off] = f2bf(rr * rr);
        } else if (EPI == EPI_SIG_BF) {
          ((unsigned short*)outp)[off] = f2bf(sigmoidf_(vv));
        } else {  // EPI_MULBF_ADDX
          float sg = bf2f(((const unsigned short*)otherp)[off]);
          ((float*)outp)[off] = xin[off] + sg * vv;
        }
      }
    }
  }
}

// ---------------- launch ----------------
extern "C" void kernel_launch(void* const* d_in, const int* in_sizes, int n_in,
                              void* d_out, int out_size, void* d_ws, size_t ws_size,
                              hipStream_t stream) {
  const float* x    = (const float*)d_in[0];
  const float* ln1w = (const float*)d_in[1];
  const float* ln1b = (const float*)d_in[2];
  const float* ln2w = (const float*)d_in[3];
  const float* ln2b = (const float*)d_in[4];
  const float* td   = (const float*)d_in[5];
  const float* tf   = (const float*)d_in[6];
  const float* tmk  = (const float*)d_in[7];
  const float* tmv  = (const float*)d_in[8];
  const float* tmr  = (const float*)d_in[9];
  const float* Wk   = (const float*)d_in[10];
  const float* Wv   = (const float*)d_in[11];
  const float* Wr   = (const float*)d_in[12];
  const float* Wo   = (const float*)d_in[13];
  const float* cmk  = (const float*)d_in[14];
  const float* cmr  = (const float*)d_in[15];
  const float* Wck  = (const float*)d_in[16];
  const float* Wcv  = (const float*)d_in[17];
  const float* Wcr  = (const float*)d_in[18];

  char* ws = (char*)d_ws;
  const size_t SLOT  = (size_t)BT * CDIM * 2;     // 64 MiB bf16 [BT,CDIM]
  const size_t SZ_W  = (size_t)CDIM * HDIM * 2;   // 32 MiB (largest weight)
  const size_t NEEDED = 4 * SLOT + SZ_W;          // 288 MiB
  if (ws_size < NEEDED) {
    sentinel_kernel<<<1, 64, 0, stream>>>((float*)d_out);
    return;
  }
  const bool twoW = (ws_size >= NEEDED + SZ_W);   // 320 MiB: keep Wck+Wcv resident

  unsigned short* slotA = (unsigned short*)(ws + 0);
  unsigned short* slotB = (unsigned short*)(ws + SLOT);
  unsigned short* slotC = (unsigned short*)(ws + 2 * SLOT);
  unsigned short* slotD = (unsigned short*)(ws + 3 * SLOT);
  unsigned short* W1    = (unsigned short*)(ws + 4 * SLOT);
  unsigned short* W2    = twoW ? (unsigned short*)(ws + 4 * SLOT + SZ_W) : W1;

  // role aliases (time-shared)
  unsigned short* xk = slotA;            // phase 1
  unsigned short* xv = slotB;
  unsigned short* xr = slotC;
  float*          kf = (float*)d_out;    // k fp32 in d_out (dies when x1 lands)
  unsigned short* vatt = slotA;          // v, then att in-place (xk dead)
  unsigned short* sratt = slotB;         // sigmoid(r)*att (xv dead)
  unsigned short* ck = slotA;            // channel-mix (att dead)
  unsigned short* cr = slotC;            // (xr dead)
  unsigned short* sigr = slotB;          // (sratt dead)
  unsigned short* hbuf = slotD;          // h row-chunks [4096, HDIM]
  float* x1 = (float*)d_out;

  const int nCC4 = CDIM * CDIM / 4;
  const int nCH4 = CDIM * HDIM / 4;
  const int gridCC = (BT / 128) * (CDIM / 128);   // 2048

  // ---- time-mix ----
  ln_mix<3><<<BT, 256, 0, stream>>>(x, ln1w, ln1b, tmk, tmv, tmr, xk, xv, xr);

  f2bf_kernel<<<2048, 256, 0, stream>>>(Wk, W1, nCC4);
  gemm_bt<EPI_F32><<<gridCC, 256, 0, stream>>>(xk, W1, kf, nullptr, nullptr, BT, CDIM, CDIM);

  f2bf_kernel<<<2048, 256, 0, stream>>>(Wv, W1, nCC4);
  gemm_bt<EPI_BF><<<gridCC, 256, 0, stream>>>(xv, W1, vatt, nullptr, nullptr, BT, CDIM, CDIM);

  wkv_kernel<<<BDIM * CDIM / 64, 64, 0, stream>>>(td, tf, kf, vatt);

  f2bf_kernel<<<2048, 256, 0, stream>>>(Wr, W1, nCC4);
  gemm_bt<EPI_SIGMUL_BF><<<gridCC, 256, 0, stream>>>(xr, W1, sratt, nullptr, vatt, BT, CDIM, CDIM);

  f2bf_kernel<<<2048, 256, 0, stream>>>(Wo, W1, nCC4);
  gemm_bt<EPI_ADDX><<<gridCC, 256, 0, stream>>>(sratt, W1, x1, x, nullptr, BT, CDIM, CDIM);

  // ---- channel-mix ----
  ln_mix<2><<<BT, 256, 0, stream>>>(x1, ln2w, ln2b, cmk, cmr, nullptr, ck, cr, nullptr);

  f2bf_kernel<<<2048, 256, 0, stream>>>(Wcr, W1, nCC4);
  gemm_bt<EPI_SIG_BF><<<gridCC, 256, 0, stream>>>(cr, W1, sigr, nullptr, nullptr, BT, CDIM, CDIM);

  if (twoW) {
    f2bf_kernel<<<2048, 256, 0, stream>>>(Wck, W1, nCH4);
    f2bf_kernel<<<2048, 256, 0, stream>>>(Wcv, W2, nCH4);
  }
  const int MC = 4096;                               // rows per chunk
  const int gridH  = (MC / 128) * (HDIM / 128);      // 2048
  const int gridKV = (MC / 128) * (CDIM / 128);      // 512
  for (int c = 0; c < BT / MC; ++c) {
    const size_t roff = (size_t)c * MC * CDIM;
    if (!twoW) f2bf_kernel<<<2048, 256, 0, stream>>>(Wck, W1, nCH4);
    gemm_bt<EPI_RELU2_BF><<<gridH, 256, 0, stream>>>(ck + roff, W1, hbuf,
                                                     nullptr, nullptr, MC, HDIM, CDIM);
    if (!twoW) f2bf_kernel<<<2048, 256, 0, stream>>>(Wcv, W2, nCH4);
    gemm_bt<EPI_MULBF_ADDX><<<gridKV, 256, 0, stream>>>(hbuf, W2, x1 + roff,
                                                        x1 + roff, sigr + roff, MC, CDIM, HDIM);
  }
}